// Round 7
// baseline (218.216 us; speedup 1.0000x reference)
//
#include <hip/hip_runtime.h>

// SSIM loss: Xt, Yt are [B=16, C=1, T=20, H=256, W=256] fp32.
// Frame f = b*20 + t contiguous 65536 floats. dr[t] = max over Yt[:,:,t].
// S per 7x7 valid window (250x250/frame); out = 1 - mean(S).

#define HH 256
#define WW 256
#define OUTW 250
#define NT 20
#define NB 16
#define NFRAMES (NT * NB)        // 320
#define STRIPS 10
#define RPS 25                   // output rows per strip
#define NWAVES (NFRAMES * STRIPS) // 3200
#define WPB 4                    // waves per block
#define NBLK2 (NWAVES / WPB)     // 800

__device__ __forceinline__ float wave_sum(float v) {
#pragma unroll
    for (int off = 32; off > 0; off >>= 1) v += __shfl_down(v, off, 64);
    return v;
}
__device__ __forceinline__ float wave_max(float v) {
#pragma unroll
    for (int off = 32; off > 0; off >>= 1) v = fmaxf(v, __shfl_down(v, off, 64));
    return v;
}

// ---------------- Pass 1: per-t max over Yt (quarter-frame blocks) ----------
__global__ __launch_bounds__(256) void dr_max_kernel(const float* __restrict__ Y,
                                                     unsigned* __restrict__ dr_bits) {
    int t = blockIdx.x;          // 0..19
    int bq = blockIdx.y;         // 0..63 : b = bq>>2, quarter = bq&3
    const float4* p = (const float4*)(Y + (size_t)((bq >> 2) * NT + t) * (HH * WW))
                      + (bq & 3) * 4096;
    float m = 0.f;               // inputs uniform [0,1) => non-negative
#pragma unroll 4
    for (int k = 0; k < 16; ++k) {
        float4 v = p[k * 256 + threadIdx.x];
        m = fmaxf(m, fmaxf(fmaxf(v.x, v.y), fmaxf(v.z, v.w)));
    }
    m = wave_max(m);
    __shared__ float smax[4];
    int lane = threadIdx.x & 63, w = threadIdx.x >> 6;
    if (lane == 0) smax[w] = m;
    __syncthreads();
    if (threadIdx.x == 0) {
        float mm = fmaxf(fmaxf(smax[0], smax[1]), fmaxf(smax[2], smax[3]));
        atomicMax(dr_bits + t, __float_as_uint(mm));  // non-neg: uint cmp == float cmp
    }
}

// ---------------- Pass 2: SSIM, shuffle-based halo (NO LDS) ----------------
// Each wave owns one (frame, strip); 64 lanes x 4 cols. Vertical running sums
// in registers; horizontal 7-tap halo comes from lanes l+1, l+2 via
// ds_bpermute (precomputed addresses). R2-R6 showed the LDS round-trip chain
// (write->fence->read, ~210 cyc/row pipe + latency) pinned all variants at
// 56-62us regardless of occupancy/ILP; bpermute removes LDS entirely.

// S scaled by 49^2 top & bottom (cancels): c1=2401*C1, c2=2401*C2.
__device__ __forceinline__ float ssim_px(float hx, float hy, float hxx, float hyy,
                                         float hxy, float c1, float c2) {
    const float cov = 49.0f / 48.0f;
    float hx2 = hx * hx, hy2 = hy * hy, hxy1 = hx * hy;
    float A1 = __builtin_fmaf(2.f, hxy1, c1);
    float B1 = hx2 + hy2 + c1;
    float t1 = __builtin_fmaf(49.f, hxx, -hx2);
    float t2 = __builtin_fmaf(49.f, hyy, -hy2);
    float t3 = __builtin_fmaf(49.f, hxy, -hxy1);
    float A2 = __builtin_fmaf(2.f * cov, t3, c2);
    float B2 = __builtin_fmaf(cov, t1 + t2, c2);
    return (A1 * A2) * __builtin_amdgcn_rcpf(B1 * B2);
}

__device__ __forceinline__ float lane_pull(float v, int addr) {
    return __int_as_float(__builtin_amdgcn_ds_bpermute(addr, __float_as_int(v)));
}

// 7-tap horizontal sums for 4 output cols from own colsums s (cols c..c+3)
// plus lane+1's (c+4..c+7) and lane+2's (c+8..c+9) via bpermute.
// h0 = s.x..s.w + n.x+n.y+n.z = full + n.p123
// h1 = h0 - s.x + n.w ; h2 = h1 - s.y + nn.x ; h3 = h2 - s.z + nn.y
__device__ __forceinline__ float4 taps7(float4 s, int a1, int a2) {
    float p123 = s.x + s.y + s.z;
    float full = p123 + s.w;
    float np123 = lane_pull(p123, a1);
    float nw    = lane_pull(s.w,  a1);
    float nnx   = lane_pull(s.x,  a2);
    float nny   = lane_pull(s.y,  a2);
    float h0 = full + np123;
    float h1 = h0 - s.x + nw;
    float h2 = h1 - s.y + nnx;
    float h3 = h2 - s.z + nny;
    return make_float4(h0, h1, h2, h3);
}

__device__ __forceinline__ void slide5(float4& sx, float4& sy, float4& sxx,
                                       float4& syy, float4& sxy,
                                       float4 xo, float4 yo, float4 xn, float4 yn) {
    sx.x += xn.x - xo.x; sx.y += xn.y - xo.y; sx.z += xn.z - xo.z; sx.w += xn.w - xo.w;
    sy.x += yn.x - yo.x; sy.y += yn.y - yo.y; sy.z += yn.z - yo.z; sy.w += yn.w - yo.w;
    sxx.x += xn.x * xn.x - xo.x * xo.x; sxx.y += xn.y * xn.y - xo.y * xo.y;
    sxx.z += xn.z * xn.z - xo.z * xo.z; sxx.w += xn.w * xn.w - xo.w * xo.w;
    syy.x += yn.x * yn.x - yo.x * yo.x; syy.y += yn.y * yn.y - yo.y * yo.y;
    syy.z += yn.z * yn.z - yo.z * yo.z; syy.w += yn.w * yn.w - yo.w * yo.w;
    sxy.x += xn.x * yn.x - xo.x * yo.x; sxy.y += xn.y * yn.y - xo.y * yo.y;
    sxy.z += xn.z * yn.z - xo.z * yo.z; sxy.w += xn.w * yn.w - xo.w * yo.w;
}

__global__ __launch_bounds__(256, 4) void ssim_kernel(const float* __restrict__ X,
                                                      const float* __restrict__ Y,
                                                      const float* __restrict__ dr_arr,
                                                      float* __restrict__ partials) {
    int w = threadIdx.x >> 6;
    int l = threadIdx.x & 63;
    int wid = blockIdx.x * WPB + w;
    int frame = wid / STRIPS;   // 0..319
    int strip = wid % STRIPS;
    int t = frame % NT;
    const float4* x4 = (const float4*)(X + (size_t)frame * (HH * WW));
    const float4* y4 = (const float4*)(Y + (size_t)frame * (HH * WW));
    int c0 = 4 * l;
    int a1 = ((l + 1) & 63) * 4;   // bpermute byte addr, loop-invariant
    int a2 = ((l + 2) & 63) * 4;   // wrapped lanes only feed masked outputs

    float dr = dr_arr[t];
    float c1 = 2401.f * (0.01f * dr) * (0.01f * dr);
    float c2 = 2401.f * (0.03f * dr) * (0.03f * dr);

    int r0 = strip * RPS;

    // vertical running column-sums (4 cols/lane) over rows r0..r0+6
    float4 sx = make_float4(0, 0, 0, 0), sy = sx, sxx = sx, syy = sx, sxy = sx;
#pragma unroll
    for (int dy = 0; dy < 7; ++dy) {
        float4 xv = x4[(r0 + dy) * 64 + l];
        float4 yv = y4[(r0 + dy) * 64 + l];
        sx.x += xv.x; sx.y += xv.y; sx.z += xv.z; sx.w += xv.w;
        sy.x += yv.x; sy.y += yv.y; sy.z += yv.z; sy.w += yv.w;
        sxx.x += xv.x * xv.x; sxx.y += xv.y * xv.y; sxx.z += xv.z * xv.z; sxx.w += xv.w * xv.w;
        syy.x += yv.x * yv.x; syy.y += yv.y * yv.y; syy.z += yv.z * yv.z; syy.w += yv.w * yv.w;
        sxy.x += xv.x * yv.x; sxy.y += xv.y * yv.y; sxy.z += xv.z * yv.z; sxy.w += xv.w * yv.w;
    }

    float acc = 0.f;
    for (int r = r0; r < r0 + RPS; ++r) {
        bool more = (r + 1 < r0 + RPS);
        float4 xo, yo, xn, yn;
        if (more) {  // issue slide loads early; latency hidden under taps+SSIM
            xo = x4[r * 64 + l];       yo = y4[r * 64 + l];
            xn = x4[(r + 7) * 64 + l]; yn = y4[(r + 7) * 64 + l];
        }

        float4 hx  = taps7(sx,  a1, a2);
        float4 hy  = taps7(sy,  a1, a2);
        float4 hxx = taps7(sxx, a1, a2);
        float4 hyy = taps7(syy, a1, a2);
        float4 hxy = taps7(sxy, a1, a2);

        // lanes 0..61: all 4 valid; lane 62 (c0=248): h0,h1 valid; lane 63: none
        if (c0 + 0 < OUTW) acc += ssim_px(hx.x, hy.x, hxx.x, hyy.x, hxy.x, c1, c2);
        if (c0 + 1 < OUTW) acc += ssim_px(hx.y, hy.y, hxx.y, hyy.y, hxy.y, c1, c2);
        if (c0 + 2 < OUTW) acc += ssim_px(hx.z, hy.z, hxx.z, hyy.z, hxy.z, c1, c2);
        if (c0 + 3 < OUTW) acc += ssim_px(hx.w, hy.w, hxx.w, hyy.w, hxy.w, c1, c2);

        if (more)  // slide window: add row r+7, drop row r
            slide5(sx, sy, sxx, syy, sxy, xo, yo, xn, yn);
    }

    acc = wave_sum(acc);
    if (l == 0) partials[wid] = acc;
}

// ---------------- Pass 3: final reduce ----------------
__global__ __launch_bounds__(256) void final_kernel(const float* __restrict__ partials,
                                                    float* __restrict__ out) {
    float s = 0.f;
    for (int i = threadIdx.x; i < NWAVES; i += 256) s += partials[i];
    s = wave_sum(s);
    __shared__ float ssum[4];
    int lane = threadIdx.x & 63, w = threadIdx.x >> 6;
    if (lane == 0) ssum[w] = s;
    __syncthreads();
    if (threadIdx.x == 0) {
        float total = ssum[0] + ssum[1] + ssum[2] + ssum[3];
        const double denom = (double)NFRAMES * OUTW * OUTW;
        out[0] = (float)(1.0 - (double)total / denom);
    }
}

extern "C" void kernel_launch(void* const* d_in, const int* in_sizes, int n_in,
                              void* d_out, int out_size, void* d_ws, size_t ws_size,
                              hipStream_t stream) {
    const float* X = (const float*)d_in[0];
    const float* Y = (const float*)d_in[1];

    float* ws = (float*)d_ws;
    unsigned* dr_bits = (unsigned*)ws;   // [0..20)
    float* partials   = ws + 32;         // [32..32+3200)

    hipMemsetAsync(d_ws, 0, NT * sizeof(float), stream);

    dim3 g1(NT, NB * 4);
    hipLaunchKernelGGL(dr_max_kernel, g1, dim3(256), 0, stream, Y, dr_bits);
    hipLaunchKernelGGL(ssim_kernel, dim3(NBLK2), dim3(256), 0, stream,
                       X, Y, (const float*)ws, partials);
    hipLaunchKernelGGL(final_kernel, dim3(1), dim3(256), 0, stream,
                       partials, (float*)d_out);
}